// Round 17
// baseline (89.012 us; speedup 1.0000x reference)
//
#include <hip/hip_runtime.h>
#include <hip/hip_bf16.h>
#include <stdint.h>

// MinGRU: B=8, S=4096, I=512, H=512 (fp32 in/out)
// R16: fused-cvt gemm reshaped for 3 blocks/CU: n-tile 64 (R5 geometry),
//      buffer = A-fp32 planes 16K + Bz 4K + Bh 4K = 24 KiB, 2 buffers =
//      48 KiB LDS -> 3 blocks/CU (12 waves/CU vs 8). Grid 2048 XCD-chunked,
//      batch<->XCD alignment preserved. Counted vmcnt(6). Consumers (K3/K4)
//      and cvt_w unchanged from R15.

typedef __attribute__((ext_vector_type(8))) short short8;   // 8 bf16
typedef __attribute__((ext_vector_type(4))) float f32x4;

#define AS1 __attribute__((address_space(1)))
#define AS3 __attribute__((address_space(3)))

__device__ inline void gload_lds16(const void* g, void* l) {
  __builtin_amdgcn_global_load_lds((AS1 uint32_t*)(g), (AS3 uint32_t*)(l), 16, 0, 0);
}

__device__ inline ushort f2bf(float f) {
  union { __hip_bfloat16 h; ushort u; } v;
  v.h = __float2bfloat16(f);
  return v.u;
}

// ---------------- K0: W fp32 -> bf16 (tiny) ----------------
__global__ void cvt_w(const float* __restrict__ wz, const float* __restrict__ wh,
                      ushort* __restrict__ wzb, ushort* __restrict__ whb) {
  int i = blockIdx.x * 256 + threadIdx.x;     // 65536 float4 per matrix
  float4 a = reinterpret_cast<const float4*>(wz)[i];
  reinterpret_cast<ushort4*>(wzb)[i] =
      make_ushort4(f2bf(a.x), f2bf(a.y), f2bf(a.z), f2bf(a.w));
  float4 b = reinterpret_cast<const float4*>(wh)[i];
  reinterpret_cast<ushort4*>(whb)[i] =
      make_ushort4(f2bf(b.x), f2bf(b.y), f2bf(b.z), f2bf(b.w));
}

// ---------------- K1: GEMM (fp32-A DMA) + gate + chunk summaries ----------
// grid 2048 (XCD-chunked): tile=(bid&7)*256+(bid>>3); bx=tile>>3 (128-row
// m-tile, 0..255), by=tile&7 (64-col n-tile, 0..7). XCD k => batch k.
// 4 waves 2x2: wave = 64 rows x 32 cols of both mats.
// LDS buffer (24 KiB): A0 [0,8K) A1 [8K,16K) fp32 planes, Bz [16K,20K),
// Bh [20K,24K) bf16. 2 buffers = 48 KiB -> 3 blocks/CU. BK=32, 16 K-steps.
// Schedule: stage(kt+1) -> vmcnt(6) -> barrier -> reads+MFMA -> barrier.
// All tiles: 64B rows, 4 slots, swizzle slot ^= (row>>1)&3 (measured 0-conf).
__global__ __launch_bounds__(256, 3) void gemm_gate(
    const float* __restrict__ x,     // [32768,512] fp32
    const ushort* __restrict__ wzb,  // [512,512] bf16
    const ushort* __restrict__ whb,  // [512,512] bf16
    const float* __restrict__ b_z,
    const float* __restrict__ b_h,
    uint* __restrict__ ab,           // [32768,512] packed (a,b) bf16
    float2* __restrict__ ABc)        // [8,512,128] chunk summaries (b,h,c)
{
  __shared__ __align__(16) char smem[49152];

  const int t  = threadIdx.x;
  const int w  = t >> 6;
  const int l  = t & 63;
  const int lm = l & 15;
  const int lk = l >> 4;
  const int wm = w >> 1, wn = w & 1;       // wave: rows wm*64.., cols wn*32..
  const int bid  = blockIdx.x;
  const int tile = (bid & 7) * 256 + (bid >> 3);   // bijective (2048 % 8 == 0)
  const int bx = tile >> 3;                // 0..255
  const int by = tile & 7;                 // 0..7
  const int m0 = bx * 128;
  const int n0 = by * 64;

  const int srow = t >> 2;     // staging: 0..63 rows per issue
  const int ssl  = t & 3;      // 16B dest slot within 64B row

  f32x4 accz[4][2], acch[4][2];
  #pragma unroll
  for (int m = 0; m < 4; ++m)
    #pragma unroll
    for (int n = 0; n < 2; ++n) {
      accz[m][n] = (f32x4){0.f, 0.f, 0.f, 0.f};
      acch[m][n] = (f32x4){0.f, 0.f, 0.f, 0.f};
    }

  auto stage = [&](int sel, int kt) {      // exactly 6 gload_lds
    char* base = smem + sel * 24576;
    const int k0 = kt * 32;
    #pragma unroll
    for (int j = 0; j < 2; ++j) {          // A fp32: 128 rows, 2 planes
      int row  = j * 64 + srow;
      int qlog = ssl ^ ((row >> 1) & 3);
      const float* xs = x + (size_t)(m0 + row) * 512 + k0 + qlog * 8;
      gload_lds16(xs,     base +        j * 4096 + w * 1024);   // plane0 (lo)
      gload_lds16(xs + 4, base + 8192 + j * 4096 + w * 1024);   // plane1 (hi)
    }
    {
      int row  = srow;                     // B: 64 rows each
      int qlog = ssl ^ ((row >> 1) & 3);
      gload_lds16(wzb + (size_t)(n0 + row) * 512 + k0 + qlog * 8,
                  base + 16384 + w * 1024);
      gload_lds16(whb + (size_t)(n0 + row) * 512 + k0 + qlog * 8,
                  base + 20480 + w * 1024);
    }
  };

  stage(0, 0);                              // 6 outstanding

  #pragma unroll
  for (int kt = 0; kt < 16; ++kt) {
    const int sel = kt & 1;
    if (kt < 15) {
      stage(sel ^ 1, kt + 1);               // 12 outstanding
      asm volatile("s_waitcnt vmcnt(6)" ::: "memory");   // tile kt landed
    } else {
      asm volatile("s_waitcnt vmcnt(0)" ::: "memory");
    }
    __builtin_amdgcn_s_barrier();           // all waves' tile-kt data landed

    const char* base = smem + sel * 24576;
    short8 af[4], bfz[2], bfh[2];
    #pragma unroll
    for (int m = 0; m < 4; ++m) {
      int row = wm * 64 + m * 16 + lm;
      int so  = ((lk ^ ((row >> 1) & 3)) << 4);
      f32x4 lo = *(const f32x4*)(base +        row * 64 + so);
      f32x4 hi = *(const f32x4*)(base + 8192 + row * 64 + so);
      short8 v;
      v[0] = (short)f2bf(lo[0]); v[1] = (short)f2bf(lo[1]);
      v[2] = (short)f2bf(lo[2]); v[3] = (short)f2bf(lo[3]);
      v[4] = (short)f2bf(hi[0]); v[5] = (short)f2bf(hi[1]);
      v[6] = (short)f2bf(hi[2]); v[7] = (short)f2bf(hi[3]);
      af[m] = v;
    }
    #pragma unroll
    for (int n = 0; n < 2; ++n) {
      int row = wn * 32 + n * 16 + lm;
      int so  = ((lk ^ ((row >> 1) & 3)) << 4);
      bfz[n] = *(const short8*)(base + 16384 + row * 64 + so);
      bfh[n] = *(const short8*)(base + 20480 + row * 64 + so);
    }
    __builtin_amdgcn_s_setprio(1);
    #pragma unroll
    for (int m = 0; m < 4; ++m)
      #pragma unroll
      for (int n = 0; n < 2; ++n) {
        accz[m][n] = __builtin_amdgcn_mfma_f32_16x16x32_bf16(af[m], bfz[n], accz[m][n], 0, 0, 0);
        acch[m][n] = __builtin_amdgcn_mfma_f32_16x16x32_bf16(af[m], bfh[n], acch[m][n], 0, 0, 0);
      }
    __builtin_amdgcn_s_setprio(0);
    __builtin_amdgcn_s_barrier();           // protect other buffer's reuse
  }

  // ---- bias loads (deferred so K-loop vmcnt stays exact) ----
  float bzv[2], bhv[2];
  #pragma unroll
  for (int n = 0; n < 2; ++n) {
    int col = n0 + wn * 32 + n * 16 + lm;
    bzv[n] = b_z[col];
    bhv[n] = b_h[col];
  }

  // ---- gate epilogue + fused chunk summaries (R5/R8-verified) ----
  // C layout: row = lk*4 + j (within 16), col = lm (m89-verified).
  float av[4][4][2], bv[4][4][2];
  #pragma unroll
  for (int m = 0; m < 4; ++m) {
    #pragma unroll
    for (int j = 0; j < 4; ++j) {
      size_t grow = (size_t)(m0 + wm * 64 + m * 16 + lk * 4 + j);
      uint* po = ab + grow * 512 + n0 + wn * 32 + lm;
      #pragma unroll
      for (int n = 0; n < 2; ++n) {
        float uz = accz[m][n][j] + bzv[n];
        float uh = acch[m][n][j] + bhv[n];
        float z  = 1.f / (1.f + __expf(-uz));
        float a  = 1.f - z;
        float bb = z * uh;
        av[m][j][n] = a;
        bv[m][j][n] = bb;
        po[n * 16] = (uint)f2bf(a) | ((uint)f2bf(bb) << 16);
      }
    }
  }

  // chunk summaries: wave rows = 2 chunks of 32 (time asc: mm, lk, j).
  #pragma unroll
  for (int cb = 0; cb < 2; ++cb) {
    #pragma unroll
    for (int n = 0; n < 2; ++n) {
      float At[2], Bt[2];
      #pragma unroll
      for (int mm = 0; mm < 2; ++mm) {
        float A = 1.f, Bv = 0.f;
        #pragma unroll
        for (int j = 0; j < 4; ++j) {
          float a = av[2 * cb + mm][j][n];
          float b = bv[2 * cb + mm][j][n];
          A  = a * A;
          Bv = a * Bv + b;
        }
        float Ag = 1.f, Bg = 0.f;
        #pragma unroll
        for (int q = 0; q < 4; ++q) {     // lk-segments in time order
          float Aq = __shfl(A,  lm + 16 * q);
          float Bq = __shfl(Bv, lm + 16 * q);
          Ag = Aq * Ag;
          Bg = Aq * Bg + Bq;
        }
        At[mm] = Ag;
        Bt[mm] = Bg;
      }
      float Achunk = At[1] * At[0];
      float Bchunk = At[1] * Bt[0] + Bt[1];
      if (lk == 0) {
        int bidx = bx >> 5;                       // batch (== XCD here)
        int c    = (bx & 31) * 4 + wm * 2 + cb;   // chunk within batch
        int col  = n0 + wn * 32 + n * 16 + lm;
        ABc[((size_t)bidx * 512 + col) * 128 + c] = make_float2(Achunk, Bchunk);
      }
    }
  }
}

// ---------------- K3: wave-parallel scan over chunk summaries ----------------
// XCD-aligned: block bid&7 = batch (matches gemm's writer XCD for ABc).
__global__ __launch_bounds__(256) void chunk_scan(
    const float2* __restrict__ ABc,   // [8,512,128]
    const float* __restrict__ h0,
    float* __restrict__ Hinit)        // [8,128,512]
{
  __shared__ float sm[128][4];
  const int w = threadIdx.x >> 6, l = threadIdx.x & 63;
  const int b   = blockIdx.x & 7;                 // batch == writer XCD
  const int h0g = (blockIdx.x >> 3) * 4;          // 0..508
  const int h   = h0g + w;

  const float2* base = ABc + ((size_t)b * 512 + h) * 128;
  float2 s1 = base[l];
  float2 s2 = base[64 + l];

  float A1 = s1.x, B1 = s1.y;
  #pragma unroll
  for (int d = 1; d < 64; d <<= 1) {
    float uA = __shfl_up(A1, d);
    float uB = __shfl_up(B1, d);
    if (l >= d) { B1 = A1 * uB + B1; A1 = A1 * uA; }
  }
  float A2 = s2.x, B2 = s2.y;
  #pragma unroll
  for (int d = 1; d < 64; d <<= 1) {
    float uA = __shfl_up(A2, d);
    float uB = __shfl_up(B2, d);
    if (l >= d) { B2 = A2 * uB + B2; A2 = A2 * uA; }
  }
  float PA = __shfl(A1, 63), PB = __shfl(B1, 63);   // prefix of chunks 0..63
  float FA = A2 * PA;
  float FB = A2 * PB + B2;

  float e1A = __shfl_up(A1, 1), e1B = __shfl_up(B1, 1);
  if (l == 0) { e1A = 1.f; e1B = 0.f; }
  float e2A = __shfl_up(FA, 1), e2B = __shfl_up(FB, 1);
  if (l == 0) { e2A = PA; e2B = PB; }

  float h0v = h0[b * 512 + h];
  sm[l][w]      = e1A * h0v + e1B;
  sm[64 + l][w] = e2A * h0v + e2B;
  __syncthreads();

  const int tt = threadIdx.x;
  if (tt < 128) {
    float4 v = *(const float4*)sm[tt];
    *(float4*)(Hinit + ((size_t)b * 128 + tt) * 512 + h0g) = v;
  }
}

// ---------------- K4: replay each chunk from Hinit, write out ----------------
// XCD-aligned: block bid&7 = batch -> ab/Hinit reads hit the writer XCD's L2.
// NT stores for out (never re-read; don't evict ab).
__global__ __launch_bounds__(256) void scan_write(
    const uint* __restrict__ ab,
    const float* __restrict__ Hinit,
    float* __restrict__ out)
{
  const int b   = blockIdx.x & 7;                 // batch == writer XCD
  const int idx = (blockIdx.x >> 3) * 256 + threadIdx.x;   // 0..16383
  const int cg  = idx & 127;           // h-group: h = cg*4 ..
  const int c   = idx >> 7;            // chunk 0..127
  const uint4* p = reinterpret_cast<const uint4*>(ab + ((size_t)(b * 4096 + c * 32)) * 512) + cg;
  float4 hv = *reinterpret_cast<const float4*>(Hinit + ((size_t)b * 128 + c) * 512 + cg * 4);
  f32x4* po = reinterpret_cast<f32x4*>(out + ((size_t)(b * 4096 + c * 32)) * 512 + cg * 4);
  uint4 u = p[0];
  #pragma unroll 4
  for (int t = 0; t < 32; ++t) {
    uint4 un = (t < 31) ? p[(size_t)(t + 1) * 128] : u;   // 2-deep prefetch
    hv.x = __uint_as_float(u.x << 16) * hv.x + __uint_as_float(u.x & 0xffff0000u);
    hv.y = __uint_as_float(u.y << 16) * hv.y + __uint_as_float(u.y & 0xffff0000u);
    hv.z = __uint_as_float(u.z << 16) * hv.z + __uint_as_float(u.z & 0xffff0000u);
    hv.w = __uint_as_float(u.w << 16) * hv.w + __uint_as_float(u.w & 0xffff0000u);
    f32x4 vv = {hv.x, hv.y, hv.z, hv.w};
    __builtin_nontemporal_store(vv, po + (size_t)t * 128);
    u = un;
  }
}

extern "C" void kernel_launch(void* const* d_in, const int* in_sizes, int n_in,
                              void* d_out, int out_size, void* d_ws, size_t ws_size,
                              hipStream_t stream) {
  const float* x   = (const float*)d_in[0];
  const float* h0  = (const float*)d_in[1];
  const float* W_z = (const float*)d_in[2];
  const float* b_z = (const float*)d_in[3];
  const float* W_h = (const float*)d_in[4];
  const float* b_h = (const float*)d_in[5];
  float* out = (float*)d_out;

  char* ws = (char*)d_ws;
  ushort* wzb   = (ushort*)(ws);                  //    524,288 B
  ushort* whb   = (ushort*)(ws + 524288);         //    524,288 B
  uint*   ab    = (uint*)  (ws + 1048576);        // 67,108,864 B
  float2* ABc   = (float2*)(ws + 68157440);       //  4,194,304 B  [8,512,128]
  float*  Hinit = (float*) (ws + 72351744);       //  2,097,152 B  [8,128,512]

  cvt_w<<<256, 256, 0, stream>>>(W_z, W_h, wzb, whb);
  gemm_gate<<<2048, 256, 0, stream>>>(x, wzb, whb, b_z, b_h, ab, ABc);
  chunk_scan<<<1024, 256, 0, stream>>>(ABc, h0, Hinit);
  scan_write<<<512, 256, 0, stream>>>(ab, Hinit, out);
}

// Round 18
// 86.372 us; speedup vs baseline: 1.0306x; 1.0306x over previous
//
#include <hip/hip_runtime.h>
#include <hip/hip_bf16.h>
#include <stdint.h>

// MinGRU: B=8, S=4096, I=512, H=512 (fp32 in/out)
// R17: R15 restored (champion, 86.77us) + scan_write prefetch depth 3.
//      gemm: fused fp32-A DMA (2 planes), 2x32KiB buffers, counted vmcnt(8),
//      XCD-chunked grid (XCD k == batch k). Consumers XCD-aligned, NT out.

typedef __attribute__((ext_vector_type(8))) short short8;   // 8 bf16
typedef __attribute__((ext_vector_type(4))) float f32x4;

#define AS1 __attribute__((address_space(1)))
#define AS3 __attribute__((address_space(3)))

__device__ inline void gload_lds16(const void* g, void* l) {
  __builtin_amdgcn_global_load_lds((AS1 uint32_t*)(g), (AS3 uint32_t*)(l), 16, 0, 0);
}

__device__ inline ushort f2bf(float f) {
  union { __hip_bfloat16 h; ushort u; } v;
  v.h = __float2bfloat16(f);
  return v.u;
}

// ---------------- K0: W fp32 -> bf16 (tiny) ----------------
__global__ void cvt_w(const float* __restrict__ wz, const float* __restrict__ wh,
                      ushort* __restrict__ wzb, ushort* __restrict__ whb) {
  int i = blockIdx.x * 256 + threadIdx.x;     // 65536 float4 per matrix
  float4 a = reinterpret_cast<const float4*>(wz)[i];
  reinterpret_cast<ushort4*>(wzb)[i] =
      make_ushort4(f2bf(a.x), f2bf(a.y), f2bf(a.z), f2bf(a.w));
  float4 b = reinterpret_cast<const float4*>(wh)[i];
  reinterpret_cast<ushort4*>(whb)[i] =
      make_ushort4(f2bf(b.x), f2bf(b.y), f2bf(b.z), f2bf(b.w));
}

// ---------------- K1: GEMM (fp32-A DMA) + gate + chunk summaries ----------
// grid 1024 (XCD-chunked): tile=(bid&7)*128+(bid>>3); bx=tile>>2 (128-row
// m-tile), by=tile&3. XCD k => bx in [k*32,(k+1)*32) => batch k exactly.
// LDS buffer (32 KiB): A planes fp32 [0,16K), Bz [16K,24K), Bh [24K,32K).
// 2 buffers, BK=32, counted vmcnt(8), swizzle slot ^= (row>>1)&3.
__global__ __launch_bounds__(256, 2) void gemm_gate(
    const float* __restrict__ x,     // [32768,512] fp32
    const ushort* __restrict__ wzb,  // [512,512] bf16
    const ushort* __restrict__ whb,  // [512,512] bf16
    const float* __restrict__ b_z,
    const float* __restrict__ b_h,
    uint* __restrict__ ab,           // [32768,512] packed (a,b) bf16
    float2* __restrict__ ABc)        // [8,512,128] chunk summaries (b,h,c)
{
  __shared__ __align__(16) char smem[65536];

  const int t  = threadIdx.x;
  const int w  = t >> 6;
  const int l  = t & 63;
  const int lm = l & 15;
  const int lk = l >> 4;
  const int wm = w >> 1, wn = w & 1;       // wave: rows wm*64.., cols wn*64..
  const int bid  = blockIdx.x;
  const int tile = (bid & 7) * 128 + (bid >> 3);   // bijective (1024 % 8 == 0)
  const int bx = tile >> 2;                // 0..255
  const int by = tile & 3;                 // 0..3
  const int m0 = bx * 128;
  const int n0 = by * 128;

  const int srow = t >> 2;     // staging: 0..63 rows per issue
  const int ssl  = t & 3;      // 16B dest slot within 64B row

  f32x4 acc[2][4][4];
  #pragma unroll
  for (int q = 0; q < 2; ++q)
    #pragma unroll
    for (int m = 0; m < 4; ++m)
      #pragma unroll
      for (int n = 0; n < 4; ++n)
        acc[q][m][n] = (f32x4){0.f, 0.f, 0.f, 0.f};

  auto stage = [&](int sel, int kt) {      // exactly 8 gload_lds
    char* base = smem + sel * 32768;
    const int k0 = kt * 32;
    #pragma unroll
    for (int j = 0; j < 2; ++j) {
      int row  = j * 64 + srow;
      int sw   = (row >> 1) & 3;
      int qlog = ssl ^ sw;
      const float* xs = x + (size_t)(m0 + row) * 512 + k0 + qlog * 8;
      gload_lds16(xs,     base +        j * 4096 + w * 1024);   // plane0 (lo)
      gload_lds16(xs + 4, base + 8192 + j * 4096 + w * 1024);   // plane1 (hi)
      gload_lds16(wzb + (size_t)(n0 + row) * 512 + k0 + qlog * 8,
                  base + 16384 + j * 4096 + w * 1024);
      gload_lds16(whb + (size_t)(n0 + row) * 512 + k0 + qlog * 8,
                  base + 24576 + j * 4096 + w * 1024);
    }
  };

  stage(0, 0);                              // 8 outstanding

  #pragma unroll
  for (int kt = 0; kt < 16; ++kt) {
    const int sel = kt & 1;
    if (kt < 15) {
      stage(sel ^ 1, kt + 1);               // 16 outstanding
      asm volatile("s_waitcnt vmcnt(8)" ::: "memory");   // tile kt landed
    } else {
      asm volatile("s_waitcnt vmcnt(0)" ::: "memory");
    }
    __builtin_amdgcn_s_barrier();           // all waves' tile-kt data landed

    const char* base = smem + sel * 32768;
    short8 af[4], bfz[4], bfh[4];
    #pragma unroll
    for (int m = 0; m < 4; ++m) {
      int row = wm * 64 + m * 16 + lm;
      int so  = ((lk ^ ((row >> 1) & 3)) << 4);
      f32x4 lo = *(const f32x4*)(base +        row * 64 + so);
      f32x4 hi = *(const f32x4*)(base + 8192 + row * 64 + so);
      short8 v;
      v[0] = (short)f2bf(lo[0]); v[1] = (short)f2bf(lo[1]);
      v[2] = (short)f2bf(lo[2]); v[3] = (short)f2bf(lo[3]);
      v[4] = (short)f2bf(hi[0]); v[5] = (short)f2bf(hi[1]);
      v[6] = (short)f2bf(hi[2]); v[7] = (short)f2bf(hi[3]);
      af[m] = v;
    }
    #pragma unroll
    for (int n = 0; n < 4; ++n) {
      int row = wn * 64 + n * 16 + lm;
      int so  = ((lk ^ ((row >> 1) & 3)) << 4);
      bfz[n] = *(const short8*)(base + 16384 + row * 64 + so);
      bfh[n] = *(const short8*)(base + 24576 + row * 64 + so);
    }
    __builtin_amdgcn_s_setprio(1);
    #pragma unroll
    for (int m = 0; m < 4; ++m)
      #pragma unroll
      for (int n = 0; n < 4; ++n) {
        acc[0][m][n] = __builtin_amdgcn_mfma_f32_16x16x32_bf16(af[m], bfz[n], acc[0][m][n], 0, 0, 0);
        acc[1][m][n] = __builtin_amdgcn_mfma_f32_16x16x32_bf16(af[m], bfh[n], acc[1][m][n], 0, 0, 0);
      }
    __builtin_amdgcn_s_setprio(0);
    __builtin_amdgcn_s_barrier();           // protect other buffer's reuse
  }

  // ---- gate epilogue + fused chunk summaries (verified) ----
  // C layout: row = lk*4 + j (within 16), col = lm (m89-verified).
  #pragma unroll
  for (int n = 0; n < 4; ++n) {
    const int col = n0 + wn * 64 + n * 16 + lm;
    const float bzn = b_z[col];
    const float bhn = b_h[col];
    float av[4][4], bv[4][4];   // [m][j]
    #pragma unroll
    for (int m = 0; m < 4; ++m) {
      #pragma unroll
      for (int j = 0; j < 4; ++j) {
        size_t grow = (size_t)(m0 + wm * 64 + m * 16 + lk * 4 + j);
        float uz = acc[0][m][n][j] + bzn;
        float uh = acc[1][m][n][j] + bhn;
        float z  = 1.f / (1.f + __expf(-uz));
        float a  = 1.f - z;
        float bb = z * uh;
        av[m][j] = a;
        bv[m][j] = bb;
        ab[grow * 512 + col] = (uint)f2bf(a) | ((uint)f2bf(bb) << 16);
      }
    }
    // chunk summaries: wave rows = 2 chunks of 32 (time asc: mm, lk, j).
    #pragma unroll
    for (int cb = 0; cb < 2; ++cb) {
      float At[2], Bt[2];
      #pragma unroll
      for (int mm = 0; mm < 2; ++mm) {
        float A = 1.f, Bv = 0.f;
        #pragma unroll
        for (int j = 0; j < 4; ++j) {
          float a = av[2 * cb + mm][j];
          float b = bv[2 * cb + mm][j];
          A  = a * A;
          Bv = a * Bv + b;
        }
        float Ag = 1.f, Bg = 0.f;
        #pragma unroll
        for (int q = 0; q < 4; ++q) {     // lk-segments in time order
          float Aq = __shfl(A,  lm + 16 * q);
          float Bq = __shfl(Bv, lm + 16 * q);
          Ag = Aq * Ag;
          Bg = Aq * Bg + Bq;
        }
        At[mm] = Ag;
        Bt[mm] = Bg;
      }
      float Achunk = At[1] * At[0];
      float Bchunk = At[1] * Bt[0] + Bt[1];
      if (lk == 0) {
        int bidx = bx >> 5;                       // batch (== XCD here)
        int c    = (bx & 31) * 4 + wm * 2 + cb;   // chunk within batch
        ABc[((size_t)bidx * 512 + col) * 128 + c] = make_float2(Achunk, Bchunk);
      }
    }
  }
}

// ---------------- K3: wave-parallel scan over chunk summaries ----------------
// XCD-aligned: block bid&7 = batch (matches gemm's writer XCD for ABc).
__global__ __launch_bounds__(256) void chunk_scan(
    const float2* __restrict__ ABc,   // [8,512,128]
    const float* __restrict__ h0,
    float* __restrict__ Hinit)        // [8,128,512]
{
  __shared__ float sm[128][4];
  const int w = threadIdx.x >> 6, l = threadIdx.x & 63;
  const int b   = blockIdx.x & 7;                 // batch == writer XCD
  const int h0g = (blockIdx.x >> 3) * 4;          // 0..508
  const int h   = h0g + w;

  const float2* base = ABc + ((size_t)b * 512 + h) * 128;
  float2 s1 = base[l];
  float2 s2 = base[64 + l];

  float A1 = s1.x, B1 = s1.y;
  #pragma unroll
  for (int d = 1; d < 64; d <<= 1) {
    float uA = __shfl_up(A1, d);
    float uB = __shfl_up(B1, d);
    if (l >= d) { B1 = A1 * uB + B1; A1 = A1 * uA; }
  }
  float A2 = s2.x, B2 = s2.y;
  #pragma unroll
  for (int d = 1; d < 64; d <<= 1) {
    float uA = __shfl_up(A2, d);
    float uB = __shfl_up(B2, d);
    if (l >= d) { B2 = A2 * uB + B2; A2 = A2 * uA; }
  }
  float PA = __shfl(A1, 63), PB = __shfl(B1, 63);   // prefix of chunks 0..63
  float FA = A2 * PA;
  float FB = A2 * PB + B2;

  float e1A = __shfl_up(A1, 1), e1B = __shfl_up(B1, 1);
  if (l == 0) { e1A = 1.f; e1B = 0.f; }
  float e2A = __shfl_up(FA, 1), e2B = __shfl_up(FB, 1);
  if (l == 0) { e2A = PA; e2B = PB; }

  float h0v = h0[b * 512 + h];
  sm[l][w]      = e1A * h0v + e1B;
  sm[64 + l][w] = e2A * h0v + e2B;
  __syncthreads();

  const int tt = threadIdx.x;
  if (tt < 128) {
    float4 v = *(const float4*)sm[tt];
    *(float4*)(Hinit + ((size_t)b * 128 + tt) * 512 + h0g) = v;
  }
}

// ---------------- K4: replay each chunk from Hinit, write out ----------------
// XCD-aligned: block bid&7 = batch -> ab/Hinit reads hit the writer XCD's L2.
// NT stores for out; software prefetch depth 3 on the ab chain.
__global__ __launch_bounds__(256) void scan_write(
    const uint* __restrict__ ab,
    const float* __restrict__ Hinit,
    float* __restrict__ out)
{
  const int b   = blockIdx.x & 7;                 // batch == writer XCD
  const int idx = (blockIdx.x >> 3) * 256 + threadIdx.x;   // 0..16383
  const int cg  = idx & 127;           // h-group: h = cg*4 ..
  const int c   = idx >> 7;            // chunk 0..127
  const uint4* p = reinterpret_cast<const uint4*>(ab + ((size_t)(b * 4096 + c * 32)) * 512) + cg;
  float4 hv = *reinterpret_cast<const float4*>(Hinit + ((size_t)b * 128 + c) * 512 + cg * 4);
  f32x4* po = reinterpret_cast<f32x4*>(out + ((size_t)(b * 4096 + c * 32)) * 512 + cg * 4);
  uint4 u0 = p[0];
  uint4 u1 = p[128];
  uint4 u2 = p[256];
  #pragma unroll 4
  for (int t = 0; t < 32; ++t) {
    uint4 u = u0;
    u0 = u1; u1 = u2;
    if (t < 29) u2 = p[(size_t)(t + 3) * 128];    // 3-deep prefetch
    hv.x = __uint_as_float(u.x << 16) * hv.x + __uint_as_float(u.x & 0xffff0000u);
    hv.y = __uint_as_float(u.y << 16) * hv.y + __uint_as_float(u.y & 0xffff0000u);
    hv.z = __uint_as_float(u.z << 16) * hv.z + __uint_as_float(u.z & 0xffff0000u);
    hv.w = __uint_as_float(u.w << 16) * hv.w + __uint_as_float(u.w & 0xffff0000u);
    f32x4 vv = {hv.x, hv.y, hv.z, hv.w};
    __builtin_nontemporal_store(vv, po + (size_t)t * 128);
  }
}

extern "C" void kernel_launch(void* const* d_in, const int* in_sizes, int n_in,
                              void* d_out, int out_size, void* d_ws, size_t ws_size,
                              hipStream_t stream) {
  const float* x   = (const float*)d_in[0];
  const float* h0  = (const float*)d_in[1];
  const float* W_z = (const float*)d_in[2];
  const float* b_z = (const float*)d_in[3];
  const float* W_h = (const float*)d_in[4];
  const float* b_h = (const float*)d_in[5];
  float* out = (float*)d_out;

  char* ws = (char*)d_ws;
  ushort* wzb   = (ushort*)(ws);                  //    524,288 B
  ushort* whb   = (ushort*)(ws + 524288);         //    524,288 B
  uint*   ab    = (uint*)  (ws + 1048576);        // 67,108,864 B
  float2* ABc   = (float2*)(ws + 68157440);       //  4,194,304 B  [8,512,128]
  float*  Hinit = (float*) (ws + 72351744);       //  2,097,152 B  [8,128,512]

  cvt_w<<<256, 256, 0, stream>>>(W_z, W_h, wzb, whb);
  gemm_gate<<<1024, 256, 0, stream>>>(x, wzb, whb, b_z, b_h, ab, ABc);
  chunk_scan<<<1024, 256, 0, stream>>>(ABc, h0, Hinit);
  scan_write<<<512, 256, 0, stream>>>(ab, Hinit, out);
}